// Round 5
// baseline (49497.852 us; speedup 1.0000x reference)
//
#include <hip/hip_runtime.h>
#include <stdint.h>

// Problem constants
#define B_  256
#define S_  512
#define E_  100
#define H_  512
#define G_  2048          // 4H
#define KH  512
#define KX  128           // padded x K-extent
#define KT  20            // K-tiles per step: 4 x-tiles then 16 h-tiles

typedef _Float16 half8 __attribute__((ext_vector_type(8)));
typedef float    f32x4 __attribute__((ext_vector_type(4)));
union V16 { f32x4 f; half8 h; };

// ws layout (bytes)
#define OFF_WC   0u          // Wc [w8][kt'20][n16][L64][e8] f16 : 2,621,440
#define OFF_XBUF 2621440u    // xbuf [t512][rg16][j4][L64][e8] f16 : 33,554,432
#define OFF_BIAS 36175872u   // [G] f32 : 8,192
#define WS_NEED  36184064u

// ---------------------------------------------------------------- prep: W (fragment-major, kt'-processing order) + bias
// idx = (((w*20 + kt')*16 + n)*64 + L)*8 + e
// gate g = n>>2, hcol-tile ht = n&3; gate-col = g*512 + w*64 + ht*16 + (L&15)
// k = (kt'<4 ? 512 + kt'*32 : (kt'-4)*32) + (L>>4)*8 + e   (x-tiles first)
__global__ void prep_wc3(const float* __restrict__ Wih, const float* __restrict__ Whh,
                         const float* __restrict__ bih, const float* __restrict__ bhh,
                         _Float16* __restrict__ Wc, float* __restrict__ bias) {
    int idx = blockIdx.x * 256 + threadIdx.x;     // < 1,310,720
    int e   = idx & 7;
    int L   = (idx >> 3) & 63;
    int n   = (idx >> 9) & 15;
    int q   = idx >> 13;                          // 0..159
    int ktp = q % 20;
    int w   = q / 20;                             // 0..7
    int g   = n >> 2, ht = n & 3;
    int gcol = g * 512 + w * 64 + ht * 16 + (L & 15);
    int k = (ktp < 4 ? 512 + ktp * 32 : (ktp - 4) * 32) + ((L >> 4) << 3) + e;
    float v = 0.f;
    if (k < KH)               v = Whh[gcol * KH + k];
    else if (k - KH < E_)     v = Wih[gcol * E_ + (k - KH)];
    Wc[idx] = (_Float16)v;
    if (idx < G_) bias[idx] = bih[idx] + bhh[idx];
}

// ---------------------------------------------------------------- prep: embed gather (fragment-major)
// xbuf idx = (((t*16 + rg)*4 + j)*64 + L)*8 + e ; batch = rg*16+(L&15), k = j*32+(L>>4)*8+e
__global__ void prep_x2(const int* __restrict__ sent, const float* __restrict__ emb,
                        _Float16* __restrict__ xbuf) {
    size_t idx = (size_t)blockIdx.x * 256 + threadIdx.x;  // < 2^24
    int e  = (int)(idx & 7);
    int L  = (int)((idx >> 3) & 63);
    int j  = (int)((idx >> 9) & 3);
    int rg = (int)((idx >> 11) & 15);
    int t  = (int)(idx >> 15);
    int b  = (rg << 4) + (L & 15);
    int k  = (j << 5) + ((L >> 4) << 3) + e;
    int tok = sent[b * S_ + t];
    float v = (k < E_) ? emb[(size_t)tok * E_ + k] : 0.f;
    xbuf[idx] = (_Float16)v;
}

// ---------------------------------------------------------------- self-sufficient per-row LSTM
// 16 blocks (one per 16-batch row) x 512 threads (8 waves, 2/SIMD).
// No inter-block communication at all: h,c live in LDS/regs; W streamed from
// L2 (2.62MB resident/XCD, shared by co-located blocks); one barrier/step.
// Wave w owns hcols [64w..64w+63] x 4 gates = 16 ntiles -> elementwise is
// wave-local (no gate exchange). B: 16-frag rolling ring that wraps across
// steps (no pipeline bubble). A (h) frags: padded [16][520] LDS, dbuf'd.
__global__ __launch_bounds__(512, 2) void lstm_seq(
    const _Float16* __restrict__ Wc, const _Float16* __restrict__ xbuf,
    const float* __restrict__ bias, float* __restrict__ out)
{
    __shared__ __align__(16) _Float16 hl[2][16][520];   // pad 8 halfs: stride 1040B = 65*16B

    const int tid  = threadIdx.x;
    const int L    = tid & 63;
    const int w    = tid >> 6;          // wave 0..7
    const int r    = blockIdx.x;        // batch-row 0..15
    const int brow0 = r << 4;
    const int lrow = L & 15;            // A-frag row (batch)
    const int kgrp = L >> 4;            // A-frag k-group

    // ---- zero both h buffers (t=0 reads zeros; branch-free k-loop)
    {
        uint32_t* p = (uint32_t*)&hl[0][0][0];
        for (int i = tid; i < 2 * 16 * 520 / 2; i += 512) p[i] = 0;
    }

    // ---- per-lane bias for the 16 ntiles (n = g*4 + ht)
    float bs[16];
#pragma unroll
    for (int n = 0; n < 16; ++n) {
        int g = n >> 2, ht = n & 3;
        bs[n] = bias[g * 512 + w * 64 + ht * 16 + (L & 15)];
    }

    // ---- c state in registers: value (batch=kgrp*4+rr, col=w*64+ht*16+(L&15))
    float cst[16];
#pragma unroll
    for (int i = 0; i < 16; ++i) cst[i] = 0.f;

    // ---- W fragment base: per-wave contiguous [kt'20][n16][L64][e8]
    const _Float16* wp = Wc + (size_t)w * (KT * 16 * 512) + (L << 3);

    // ---- x frags for t=0
    V16 xf[4];
    {
        const _Float16* xp = xbuf + ((size_t)0 * 16 + r) * 4 * 512 + (L << 3);
#pragma unroll
        for (int j = 0; j < 4; ++j) xf[j].f = *(const f32x4*)(xp + j * 512);
    }

    // ---- B ring prologue: kt'=0 fragments
    V16 Bv[16];
#pragma unroll
    for (int n = 0; n < 16; ++n) Bv[n].f = *(const f32x4*)(wp + (size_t)n * 512);

    __syncthreads();   // h zeros visible

    for (int t = 0; t < S_; ++t) {
        const _Float16 (*hc)[520] = hl[t & 1];
        _Float16 (*hn)[520]       = hl[(t + 1) & 1];

        f32x4 acc[16];
#pragma unroll
        for (int n = 0; n < 16; ++n) { f32x4 a = {bs[n], bs[n], bs[n], bs[n]}; acc[n] = a; }

        // ---- x K-tiles (kt' 0..3); ring loads kt'+1
#pragma unroll
        for (int ktp = 0; ktp < 4; ++ktp) {
#pragma unroll
            for (int n = 0; n < 16; ++n) {
                acc[n] = __builtin_amdgcn_mfma_f32_16x16x32_f16(xf[ktp].h, Bv[n].h, acc[n], 0, 0, 0);
                Bv[n].f = *(const f32x4*)(wp + ((size_t)(ktp + 1) * 16 + n) * 512);
            }
        }

        // ---- h K-tiles (kt' 4..19 <=> j 0..15); A dbuf from LDS; ring wraps to kt'0
        V16 Ac, An;
        Ac.f = *(const f32x4*)(&hc[lrow][kgrp * 8]);
#pragma unroll
        for (int j = 0; j < 16; ++j) {
            if (j < 15) An.f = *(const f32x4*)(&hc[lrow][(j + 1) * 32 + kgrp * 8]);
#pragma unroll
            for (int n = 0; n < 16; ++n) {
                acc[n] = __builtin_amdgcn_mfma_f32_16x16x32_f16(Ac.h, Bv[n].h, acc[n], 0, 0, 0);
                Bv[n].f = *(const f32x4*)(wp + ((size_t)((j + 5) % 20) * 16 + n) * 512);
            }
            Ac = An;
        }

        // ---- next-step x frags (issued early; land during elementwise + barrier)
        {
            const int tn = (t + 1) & (S_ - 1);
            const _Float16* xp = xbuf + ((size_t)tn * 16 + r) * 4 * 512 + (L << 3);
#pragma unroll
            for (int j = 0; j < 4; ++j) xf[j].f = *(const f32x4*)(xp + j * 512);
        }

        // ---- elementwise cell update (wave-local; 16 values/thread)
        const int colb = w * 64 + (L & 15);
        const int bb   = kgrp * 4;
#pragma unroll
        for (int ht = 0; ht < 4; ++ht) {
#pragma unroll
            for (int rr = 0; rr < 4; ++rr) {
                float iv = acc[ht][rr];          // n = g*4+ht
                float fv = acc[4 + ht][rr];
                float gv = acc[8 + ht][rr];
                float ov = acc[12 + ht][rr];
                float si = 1.f / (1.f + __expf(-iv));
                float sf = 1.f / (1.f + __expf(-fv));
                float so = 1.f / (1.f + __expf(-ov));
                float tg = 1.f - 2.f / (__expf(2.f * gv) + 1.f);
                float cn = sf * cst[ht * 4 + rr] + si * tg;
                cst[ht * 4 + rr] = cn;
                float hv = so * (1.f - 2.f / (__expf(2.f * cn) + 1.f));
                const int col = colb + ht * 16;
                const int b   = bb + rr;
                if (t == S_ - 1) {
                    out[(size_t)(brow0 + b) * H_ + col] = hv;
                } else {
                    hn[b][col] = (_Float16)hv;
                }
            }
        }
        __syncthreads();   // h_{t+1} visible to all waves
    }
}

// ---------------------------------------------------------------- launch
extern "C" void kernel_launch(void* const* d_in, const int* in_sizes, int n_in,
                              void* d_out, int out_size, void* d_ws, size_t ws_size,
                              hipStream_t stream) {
    (void)in_sizes; (void)n_in; (void)out_size;
    if (ws_size < WS_NEED) return;

    const int*   sent = (const int*)d_in[0];
    const float* emb  = (const float*)d_in[1];
    const float* Wih  = (const float*)d_in[2];
    const float* Whh  = (const float*)d_in[3];
    const float* bih  = (const float*)d_in[4];
    const float* bhh  = (const float*)d_in[5];

    char* ws = (char*)d_ws;
    _Float16* Wc   = (_Float16*)(ws + OFF_WC);
    _Float16* xbuf = (_Float16*)(ws + OFF_XBUF);
    float*    bias = (float*)(ws + OFF_BIAS);

    prep_wc3<<<(8 * KT * 16 * 64 * 8) / 256, 256, 0, stream>>>(Wih, Whh, bih, bhh, Wc, bias);
    prep_x2<<<(S_ * B_ * KX) / 256, 256, 0, stream>>>(sent, emb, xbuf);
    lstm_seq<<<16, 512, 0, stream>>>(Wc, xbuf, bias, (float*)d_out);
}

// Round 7
// 1303.861 us; speedup vs baseline: 37.9625x; 37.9625x over previous
//
#include <hip/hip_runtime.h>
#include <stdint.h>

// Problem constants
#define B_  256
#define S_  512
#define E_  100
#define H_  512
#define G_  2048          // 4H
#define KH_ 512

typedef _Float16 half8 __attribute__((ext_vector_type(8)));
typedef float    f32x4 __attribute__((ext_vector_type(4)));
union V16 { f32x4 f; half8 h; unsigned long long q[2]; };

// ws layout (bytes) — total 29.9MB, well under the proven 36.7MB envelope
#define OFF_WC   0u          // Wc [c16][w4][n2][s20][L64][e8] f16 : 2,621,440
#define OFF_HBT  2621440u    // hbt [2][256 b][256 cp] u64 tagged-h : 1,048,576
#define OFF_XB3  3670016u    // xb3 [t512][rg16][j3][L64][e8] f16   : 25,165,824
#define OFF_XTL  28835840u   // xtl [t512][b256][e4] f16            : 1,048,576
#define OFF_BIAS 29884416u   // [G] f32                             : 8,192
#define WS_NEED  29892608u

// LDS carve (dynamic)
#define LDS_W   131072       // W h-part [w4][n2][kt16][L64][16B]
#define LDS_A   16384        // h A-tile [16 rows][512 halfs], XOR-swizzled
#define LDS_G   8448         // float[4][16][33]
#define LDS_TOT (LDS_W + LDS_A + LDS_G)   // 155,904

// ---------------------------------------------------------------- prep: W (fragment-major) + bias
// idx = ((((c*4+w)*2+n)*20+s)*64+L)*8+e
// gate col g = w*512 + c*32 + n*16 + (L&15)
// k(s) : s<16 -> h k = s*32+kl ; s=16..18 -> x k = (s-16)*32+kl ; s=19 -> x k = 96+kl
__global__ void prep_wc4(const float* __restrict__ Wih, const float* __restrict__ Whh,
                         const float* __restrict__ bih, const float* __restrict__ bhh,
                         _Float16* __restrict__ Wc, float* __restrict__ bias) {
    int idx = blockIdx.x * 256 + threadIdx.x;     // < 1,310,720
    int e  = idx & 7;
    int L  = (idx >> 3) & 63;
    int q  = idx >> 9;                            // < 2560
    int s  = q % 20;
    int qq = q / 20;
    int n  = qq & 1;
    int w  = (qq >> 1) & 3;
    int c  = qq >> 3;
    int g  = (w << 9) + (c << 5) + (n << 4) + (L & 15);
    int kl = ((L >> 4) << 3) + e;
    float v = 0.f;
    if (s < 16) {
        v = Whh[g * KH_ + (s << 5) + kl];
    } else {
        int xk = (s < 19) ? ((s - 16) << 5) + kl : 96 + kl;
        if (xk < E_) v = Wih[g * E_ + xk];
    }
    Wc[idx] = (_Float16)v;
    if (idx < G_) bias[idx] = bih[idx] + bhh[idx];
}

// ---------------------------------------------------------------- prep: x main (k 0..95, fragment-major)
__global__ void prep_x3(const int* __restrict__ sent, const float* __restrict__ emb,
                        _Float16* __restrict__ xb3) {
    size_t idx = (size_t)blockIdx.x * 256 + threadIdx.x;   // < 12,582,912
    int e  = (int)(idx & 7);
    int L  = (int)((idx >> 3) & 63);
    int q  = (int)(idx >> 9);
    int j  = q % 3;
    int qq = q / 3;
    int rg = qq & 15;
    int t  = qq >> 4;
    int b  = (rg << 4) + (L & 15);
    int k  = (j << 5) + ((L >> 4) << 3) + e;     // < 96 < E_
    int tok = sent[b * S_ + t];
    xb3[idx] = (_Float16)emb[(size_t)tok * E_ + k];
}

// ---------------------------------------------------------------- prep: x tail (k 96..99)
__global__ void prep_xtail(const int* __restrict__ sent, const float* __restrict__ emb,
                           _Float16* __restrict__ xtl) {
    int idx = blockIdx.x * 256 + threadIdx.x;    // < 524,288
    int e = idx & 3;
    int b = (idx >> 2) & 255;
    int t = idx >> 10;
    int tok = sent[b * S_ + t];
    xtl[idx] = (_Float16)emb[(size_t)tok * E_ + 96 + e];
}

// ---------------------------------------------------------------- persistent LSTM
// 256 blocks = 16 rows x 16 hcol-tiles; W h-part in LDS; h exchange via
// SELF-VALIDATING tagged u64 words (relaxed agent atomics, LLC-direct):
// word = [h0,h1 : tag]. No flags, no fences, no RMW, no drain barriers.
// Parity double-buffer + per-call memset kill all overwrite/stale races.
__global__ __launch_bounds__(256, 1) void lstm_persist(
    const _Float16* __restrict__ Wc, unsigned long long* __restrict__ hbt,
    const _Float16* __restrict__ xb3, const _Float16* __restrict__ xtl,
    const float* __restrict__ bias, float* __restrict__ out)
{
    extern __shared__ __align__(16) char smem[];
    char* wl = smem;                       // W h-part fragments
    char* al = smem + LDS_W;               // A tile (swizzled)
    float (*gbuf)[16][33] = reinterpret_cast<float(*)[16][33]>(smem + LDS_W + LDS_A);

    const int tid = threadIdx.x;
    const int L   = tid & 63;
    const int w   = tid >> 6;              // wave = gate type (0:i 1:f 2:g 3:o)
    const int bx  = blockIdx.x;
    const int xcd = bx & 7;                // XCD-aware swizzle (perf heuristic)
    const int kk_ = bx >> 3;
    const int r   = (xcd << 1) | (kk_ >> 4);   // batch-row 0..15
    const int c   = kk_ & 15;                  // hcol-tile 0..15
    const int brow0 = r << 4;
    const int hcol0 = c << 5;

    // ---- W preload: slots 0..15 (h) -> LDS; slots 16..19 (x) -> regs
    const _Float16* wp0 = Wc + (size_t)((((c << 2) + w) << 1)) * (20 * 512) + (L << 3);
    const _Float16* wp1 = wp0 + 20 * 512;
#pragma unroll
    for (int n = 0; n < 2; ++n)
#pragma unroll
        for (int kt = 0; kt < 16; ++kt) {
            f32x4 v = *reinterpret_cast<const f32x4*>((n ? wp1 : wp0) + (kt << 9));
            *reinterpret_cast<f32x4*>(wl + ((((w << 1) + n) * 16 + kt) << 10) + (L << 4)) = v;
        }
    V16 wx[2][4];
#pragma unroll
    for (int n = 0; n < 2; ++n)
#pragma unroll
        for (int j = 0; j < 4; ++j)
            wx[n][j].f = *reinterpret_cast<const f32x4*>((n ? wp1 : wp0) + ((16 + j) << 9));

    // ---- per-thread cell-state mapping: thread owns h/c at (bl, j0), (bl, j0+1)
    const int bl = tid >> 4;
    const int j0 = (tid << 1) & 31;
    const float bi0 = bias[hcol0 + j0],         bi1 = bias[hcol0 + j0 + 1];
    const float bf0 = bias[512  + hcol0 + j0],  bf1 = bias[512  + hcol0 + j0 + 1];
    const float bg0 = bias[1024 + hcol0 + j0],  bg1 = bias[1024 + hcol0 + j0 + 1];
    const float bo0 = bias[1536 + hcol0 + j0],  bo1 = bias[1536 + hcol0 + j0 + 1];
    float cc0 = 0.f, cc1 = 0.f;

    const int arow = L & 15;
    const int agrp = L >> 4;
    const int ard  = arow << 10;
    const int asw  = (arow & 7) << 4;

    // ---- x fragments for t=0 (3 main tiles + tail tile)
    V16 xf[3], xt;
    {
        const _Float16* xp = xb3 + ((size_t)r * 3) * 512 + (L << 3);
#pragma unroll
        for (int j = 0; j < 3; ++j) xf[j].f = *reinterpret_cast<const f32x4*>(xp + j * 512);
        unsigned long long tv = *reinterpret_cast<const unsigned long long*>(
            xtl + (size_t)(brow0 + arow) * 4);
        xt.q[0] = (agrp == 0) ? tv : 0ull;
        xt.q[1] = 0ull;
    }

    for (int t = 0; t < S_; ++t) {
        // ---- 1. x-part MFMA (4 tiles; independent of h)
        f32x4 a00 = {0,0,0,0}, a01 = {0,0,0,0}, a10 = {0,0,0,0}, a11 = {0,0,0,0};
#pragma unroll
        for (int j = 0; j < 4; ++j) {
            half8 a = (j < 3) ? xf[j].h : xt.h;
            if (j & 1) {
                a01 = __builtin_amdgcn_mfma_f32_16x16x32_f16(a, wx[0][j].h, a01, 0, 0, 0);
                a11 = __builtin_amdgcn_mfma_f32_16x16x32_f16(a, wx[1][j].h, a11, 0, 0, 0);
            } else {
                a00 = __builtin_amdgcn_mfma_f32_16x16x32_f16(a, wx[0][j].h, a00, 0, 0, 0);
                a10 = __builtin_amdgcn_mfma_f32_16x16x32_f16(a, wx[1][j].h, a10, 0, 0, 0);
            }
        }

        // ---- 2. retry-load tagged h words until tag==t, then stage to LDS
        if (t > 0) {
            const unsigned long long* hq = hbt + ((size_t)(t & 1) << 16) + ((size_t)brow0 << 8);
            const unsigned tag = (unsigned)t;
            unsigned long long vv[16];
            int rounds = 0;
            bool again = true;
            while (again) {
#pragma unroll
                for (int j = 0; j < 16; ++j)
                    vv[j] = __hip_atomic_load(hq + (j << 8) + tid,
                                              __ATOMIC_RELAXED, __HIP_MEMORY_SCOPE_AGENT);
                again = false;
#pragma unroll
                for (int j = 0; j < 16; ++j) again |= ((unsigned)vv[j] != tag);
                if (++rounds > 4000000) break;   // safety valve
            }
            __builtin_amdgcn_sched_barrier(0);
            // stage: row j, col-pair tid (u32 of 2 halfs), XOR-swizzled granules
#pragma unroll
            for (int j = 0; j < 16; ++j) {
                unsigned pack = (unsigned)(vv[j] >> 32);
                *reinterpret_cast<unsigned*>(
                    al + (j << 10) + ((((tid >> 2) ^ (j & 7))) << 4) + ((tid & 3) << 2)) = pack;
            }
        }
        __syncthreads();                   // barrier 1: A tile ready

        // ---- 3. h-part MFMA: A from swizzled LDS, B from LDS
        if (t > 0) {
#pragma unroll
            for (int kt = 0; kt < 16; ++kt) {
                V16 av, b0, b1;
                av.f = *reinterpret_cast<const f32x4*>(
                    al + ard + ((((kt << 2) + agrp) << 4) ^ asw));
                b0.f = *reinterpret_cast<const f32x4*>(wl + (((w << 5) + kt) << 10) + (L << 4));
                b1.f = *reinterpret_cast<const f32x4*>(wl + (((w << 5) + 16 + kt) << 10) + (L << 4));
                if (kt & 1) {
                    a01 = __builtin_amdgcn_mfma_f32_16x16x32_f16(av.h, b0.h, a01, 0, 0, 0);
                    a11 = __builtin_amdgcn_mfma_f32_16x16x32_f16(av.h, b1.h, a11, 0, 0, 0);
                } else {
                    a00 = __builtin_amdgcn_mfma_f32_16x16x32_f16(av.h, b0.h, a00, 0, 0, 0);
                    a10 = __builtin_amdgcn_mfma_f32_16x16x32_f16(av.h, b1.h, a10, 0, 0, 0);
                }
            }
        }
        f32x4 g0 = a00 + a01;
        f32x4 g1 = a10 + a11;
        {
            const int grb = agrp << 2;     // C/D: col=lane&15, row=(lane>>4)*4+reg
            const int gc  = L & 15;
#pragma unroll
            for (int rr = 0; rr < 4; ++rr) {
                gbuf[w][grb + rr][gc]      = g0[rr];
                gbuf[w][grb + rr][16 + gc] = g1[rr];
            }
        }

        // ---- 4. prefetch next step's x fragments (land during barrier+elementwise)
        V16 xn[3], xnt;
        {
            const int tn = (t + 1) & (S_ - 1);
            const _Float16* xp = xb3 + (((size_t)tn * 16 + r) * 3) * 512 + (L << 3);
#pragma unroll
            for (int j = 0; j < 3; ++j) xn[j].f = *reinterpret_cast<const f32x4*>(xp + j * 512);
            unsigned long long tv = *reinterpret_cast<const unsigned long long*>(
                xtl + ((size_t)tn * 256 + brow0 + arow) * 4);
            xnt.q[0] = (agrp == 0) ? tv : 0ull;
            xnt.q[1] = 0ull;
        }
        __syncthreads();                   // barrier 2: gates ready

        // ---- 5. elementwise cell update + tagged publish
        float i0 = gbuf[0][bl][j0]     + bi0, i1 = gbuf[0][bl][j0 + 1] + bi1;
        float f0 = gbuf[1][bl][j0]     + bf0, f1 = gbuf[1][bl][j0 + 1] + bf1;
        float gg0= gbuf[2][bl][j0]     + bg0, gg1= gbuf[2][bl][j0 + 1] + bg1;
        float o0 = gbuf[3][bl][j0]     + bo0, o1 = gbuf[3][bl][j0 + 1] + bo1;
        float si0 = 1.f / (1.f + __expf(-i0));
        float sf0 = 1.f / (1.f + __expf(-f0));
        float so0 = 1.f / (1.f + __expf(-o0));
        float tg0 = tanhf(gg0);
        float si1 = 1.f / (1.f + __expf(-i1));
        float sf1 = 1.f / (1.f + __expf(-f1));
        float so1 = 1.f / (1.f + __expf(-o1));
        float tg1 = tanhf(gg1);
        cc0 = sf0 * cc0 + si0 * tg0;
        cc1 = sf1 * cc1 + si1 * tg1;
        float h0 = so0 * tanhf(cc0);
        float h1 = so1 * tanhf(cc1);

        if (t == S_ - 1) {
            float* op = out + (size_t)(brow0 + bl) * H_ + hcol0 + j0;
            op[0] = h0; op[1] = h1;
        } else {
            _Float16 hh0 = (_Float16)h0, hh1 = (_Float16)h1;
            unsigned pack = ((unsigned)*(unsigned short*)&hh1 << 16)
                          |  (unsigned)*(unsigned short*)&hh0;
            unsigned long long word = ((unsigned long long)pack << 32)
                                    |  (unsigned long long)(unsigned)(t + 1);
            __hip_atomic_store(hbt + ((size_t)((t + 1) & 1) << 16)
                                   + ((size_t)(brow0 + bl) << 8) + (c << 4) + (tid & 15),
                               word, __ATOMIC_RELAXED, __HIP_MEMORY_SCOPE_AGENT);
        }

        // rotate x prefetch
#pragma unroll
        for (int j = 0; j < 3; ++j) xf[j] = xn[j];
        xt = xnt;
    }
}

// ---------------------------------------------------------------- launch
extern "C" void kernel_launch(void* const* d_in, const int* in_sizes, int n_in,
                              void* d_out, int out_size, void* d_ws, size_t ws_size,
                              hipStream_t stream) {
    (void)in_sizes; (void)n_in; (void)out_size;
    if (ws_size < WS_NEED) return;

    const int*   sent = (const int*)d_in[0];
    const float* emb  = (const float*)d_in[1];
    const float* Wih  = (const float*)d_in[2];
    const float* Whh  = (const float*)d_in[3];
    const float* bih  = (const float*)d_in[4];
    const float* bhh  = (const float*)d_in[5];

    char* ws = (char*)d_ws;
    _Float16*           Wc   = (_Float16*)(ws + OFF_WC);
    unsigned long long* hbt  = (unsigned long long*)(ws + OFF_HBT);
    _Float16*           xb3  = (_Float16*)(ws + OFF_XB3);
    _Float16*           xtl  = (_Float16*)(ws + OFF_XTL);
    float*              bias = (float*)(ws + OFF_BIAS);

    (void)hipFuncSetAttribute(reinterpret_cast<const void*>(lstm_persist),
                              hipFuncAttributeMaxDynamicSharedMemorySize, LDS_TOT);

    (void)hipMemsetAsync(hbt, 0, 2 * 256 * 256 * sizeof(unsigned long long), stream);

    prep_wc4<<<(16 * 4 * 2 * 20 * 64 * 8) / 256, 256, 0, stream>>>(Wih, Whh, bih, bhh, Wc, bias);
    prep_x3<<<(S_ * 16 * 3 * 512) / 256, 256, 0, stream>>>(sent, emb, xb3);
    prep_xtail<<<(S_ * B_ * 4) / 256, 256, 0, stream>>>(sent, emb, xtl);
    lstm_persist<<<256, 256, LDS_TOT, stream>>>(Wc, hbt, xb3, xtl, bias, (float*)d_out);
}